// Round 2
// baseline (651.252 us; speedup 1.0000x reference)
//
#include <hip/hip_runtime.h>
#include <cmath>

typedef __attribute__((ext_vector_type(8))) short short8;
typedef __attribute__((ext_vector_type(8))) unsigned short ushort8;
typedef __attribute__((ext_vector_type(4))) float f32x4;
typedef __attribute__((ext_vector_type(2))) float f32x2;
typedef __attribute__((ext_vector_type(4))) unsigned int uint4v;
typedef __attribute__((ext_vector_type(2))) int int2v;

#define EPB 4096
#define BCAP 20480   // per-bucket capacity; expected 16384 +/- 128, 25% slack

__device__ inline float bf16_lo(unsigned int p) {
  union { unsigned int i; float f; } v; v.i = p << 16; return v.f;
}
__device__ inline float bf16_hi(unsigned int p) {
  union { unsigned int i; float f; } v; v.i = p & 0xffff0000u; return v.f;
}
__device__ inline f32x2 bf2(unsigned int p) {
  union { unsigned int i; float f; } lo, hi;
  lo.i = p << 16;
  hi.i = p & 0xffff0000u;
  return (f32x2){lo.f, hi.f};
}
__device__ inline float bf16u(unsigned short w) {
  union { unsigned int i; float f; } v; v.i = (unsigned int)w << 16; return v.f;
}
__device__ inline unsigned short f32_to_bf16(float f) {
  union { float f; unsigned int i; } v; v.f = f;
  unsigned int x = v.i;
  x += 0x7fffu + ((x >> 16) & 1u);   // RNE; no NaN in this workload
  return (unsigned short)(x >> 16);
}
// forced packed f32 add (VOP3P); compiler wasn't emitting it from vector '+'
__device__ inline f32x2 pk_add(f32x2 a, f32x2 b) {
  f32x2 d;
  asm("v_pk_add_f32 %0, %1, %2" : "=v"(d) : "v"(a), "v"(b));
  return d;
}

// ---------- pass 1: bin edges into 512-row buckets (fixed-capacity regions) --
// packed entry: (r & 511) << 17 | c   (c < 2^17, valid for N <= 131072)
__global__ __launch_bounds__(256) void bin_k(const int* __restrict__ rows,
                                             const int* __restrict__ cols,
                                             int* __restrict__ bucket_cursor,
                                             unsigned int* __restrict__ binned, int E) {
  __shared__ int lhist[256];
  __shared__ int gbase[256];
  __shared__ int loff[256];
  const int t = threadIdx.x;
  const int base = blockIdx.x * EPB;
  lhist[t] = 0;
  __syncthreads();

  int bk[16];
  unsigned int pk[16];
#pragma unroll
  for (int j = 0; j < 16; ++j) {
    int e = base + j * 256 + t;
    if (e < E) {
      int r = rows[e];
      int c = cols[e];
      bk[j] = r >> 9;
      pk[j] = ((unsigned int)(r & 511) << 17) | (unsigned int)c;
      atomicAdd(&lhist[bk[j]], 1);
    } else {
      bk[j] = -1;
    }
  }
  __syncthreads();
  if (lhist[t] > 0) gbase[t] = atomicAdd(&bucket_cursor[t], lhist[t]);
  loff[t] = 0;
  __syncthreads();
#pragma unroll
  for (int j = 0; j < 16; ++j) {
    if (bk[j] >= 0) {
      int rank = gbase[bk[j]] + atomicAdd(&loff[bk[j]], 1);
      if (rank < BCAP) binned[(size_t)bk[j] * BCAP + rank] = pk[j];
    }
  }
}

// ---------- pass 2: per-bucket CSR build + degree-sorted permutation ----------
__global__ __launch_bounds__(1024) void bucket_csr_k(const unsigned int* __restrict__ binned,
                                                     const int* __restrict__ bucket_cursor,
                                                     int2v* __restrict__ rowse,
                                                     float* __restrict__ dis,
                                                     int* __restrict__ col_sorted,
                                                     int* __restrict__ perm,
                                                     int N, float fill) {
  __shared__ int lcnt[512];
  __shared__ int lscan[512];
  __shared__ int dh[512];
  __shared__ int ds2[512];
  const int b = blockIdx.x;
  const int t = threadIdx.x;
  const int start = b * BCAP;
  int cnt = bucket_cursor[b];
  if (cnt > BCAP) cnt = BCAP;
  const int endb = start + cnt;
  const int rbase = b << 9;

  if (t < 512) lcnt[t] = 0;
  __syncthreads();
  for (int i = start + t; i < endb; i += 1024)
    atomicAdd(&lcnt[binned[i] >> 17], 1);
  __syncthreads();

  int v = (t < 512) ? lcnt[t] : 0;
  if (t < 512) lscan[t] = v;
  __syncthreads();
  for (int off = 1; off < 512; off <<= 1) {
    int add = (t < 512 && t >= off) ? lscan[t - off] : 0;
    __syncthreads();
    if (t < 512) lscan[t] += add;
    __syncthreads();
  }

  if (t < 512) {
    int excl = lscan[t] - v;
    int r = rbase + t;
    if (r < N) {
      rowse[r] = (int2v){start + excl, start + excl + v};
      float d = (float)v + fill;
      dis[r] = d > 0.f ? rsqrtf(d) : 0.f;
    }
    lcnt[t] = excl;   // cursor for scatter pass
  }

  // ---- degree-sort permutation (counting sort, descending degree) ----
  if (t < 512) dh[t] = 0;
  __syncthreads();
  int key = 0;
  if (t < 512) {
    key = 511 - (v < 511 ? v : 511);   // descending degree
    atomicAdd(&dh[key], 1);
  }
  __syncthreads();
  if (t < 512) ds2[t] = dh[t];
  __syncthreads();
  for (int off = 1; off < 512; off <<= 1) {
    int add = (t < 512 && t >= off) ? ds2[t - off] : 0;
    __syncthreads();
    if (t < 512) ds2[t] += add;
    __syncthreads();
  }
  int base2 = 0;
  if (t < 512) base2 = ds2[t] - dh[t];   // exclusive
  __syncthreads();
  if (t < 512) dh[t] = base2;            // cursor
  __syncthreads();
  if (t < 512) {
    int rank = atomicAdd(&dh[key], 1);
    perm[(b << 9) + rank] = rbase + t;
  }
  __syncthreads();

  // ---- scatter cols to CSR slots ----
  for (int i = start + t; i < endb; i += 1024) {
    unsigned int pk = binned[i];
    int rl = (int)(pk >> 17);
    int c = (int)(pk & 0x1FFFFu);
    int pos = atomicAdd(&lcnt[rl], 1);
    col_sorted[start + pos] = c;
  }
}

// ---------- cast + transpose weights to bf16: Wt[n][k] = W[k][n] ----------
__global__ __launch_bounds__(256) void cast_w_k(const float* __restrict__ W1,
                                                const float* __restrict__ W2,
                                                const float* __restrict__ W3,
                                                unsigned short* __restrict__ W1t,
                                                unsigned short* __restrict__ W2t,
                                                unsigned short* __restrict__ W3b,
                                                int FIN) {
  int g = blockIdx.x * 256 + threadIdx.x;
  int n1 = FIN * 128;
  if (g < n1) {
    int n = g & 127, k = g >> 7;
    W1t[n * FIN + k] = f32_to_bf16(W1[(size_t)k * 128 + n]);
  } else if (g < n1 + 128 * 128) {
    int gg = g - n1;
    int n = gg & 127, k = gg >> 7;
    W2t[n * 128 + k] = f32_to_bf16(W2[k * 128 + n]);
  } else if (g < n1 + 128 * 128 + 16 * 128) {
    int gg = g - n1 - 128 * 128;
    W3b[gg] = f32_to_bf16(W3[gg]);   // W3 is already [cls][k]
  }
}

// ---------- bf16 MFMA GEMM: C[M][128] = dis[m] * (A[M][K] * Wt^T) ----------
// BM=128, BN=128(full), BK=32; 4 waves as 2x2 over (M,N), 64x64 per wave,
// acc[4][4], 16 MFMA : 8 ds_read_b128 per K-step; register double-buffer.
// (m93 ladder step: 64^2 -> 128^2 tile was 1.5x on this structure.)
__global__ __launch_bounds__(256) void gemm_k(const void* __restrict__ Aq, int a_is_f32,
                                              int M, int K,
                                              const unsigned short* __restrict__ Bt,
                                              const float* __restrict__ dis,
                                              unsigned short* __restrict__ C) {
  __shared__ unsigned short Al[128 * 40];   // stride 40 (= 32 + 8 pad, 2-way = free)
  __shared__ unsigned short Bl[128 * 40];
  const int t = threadIdx.x;
  const int bm = blockIdx.x * 128;
  const int lane = t & 63;
  const int wave = t >> 6;
  const int wm = (wave >> 1) * 64;
  const int wn = (wave & 1) * 64;
  const int l15 = lane & 15;
  const int l4 = lane >> 4;

  f32x4 acc[4][4];
#pragma unroll
  for (int a = 0; a < 4; ++a)
#pragma unroll
    for (int b = 0; b < 4; ++b) acc[a][b] = (f32x4){0.f, 0.f, 0.f, 0.f};

  const int am = t >> 1;        // 0..127
  const int ak = (t & 1) * 16;  // 0,16
  const int bn = t >> 1;        // 0..127
  const int bk = (t & 1) * 16;  // 0,16
  const int arow = bm + am;
  const bool arow_ok = arow < M;

  auto load_a = [&](int k0, ushort8& o0, ushort8& o1) {
    o0 = (ushort8){0, 0, 0, 0, 0, 0, 0, 0};
    o1 = (ushort8){0, 0, 0, 0, 0, 0, 0, 0};
    if (arow_ok) {
      if (a_is_f32) {
        const float* p = (const float*)Aq + (size_t)arow * K + k0 + ak;
#pragma unroll
        for (int j = 0; j < 8; ++j) o0[j] = f32_to_bf16(p[j]);
#pragma unroll
        for (int j = 0; j < 8; ++j) o1[j] = f32_to_bf16(p[8 + j]);
      } else {
        const unsigned short* p = (const unsigned short*)Aq + (size_t)arow * K + k0 + ak;
        o0 = *(const ushort8*)p;
        o1 = *(const ushort8*)(p + 8);
      }
    }
  };

  ushort8 av0, av1;
  load_a(0, av0, av1);
  ushort8 bv0 = *(const ushort8*)(Bt + (size_t)bn * K + bk);
  ushort8 bv1 = *(const ushort8*)(Bt + (size_t)bn * K + bk + 8);

  for (int k0 = 0; k0 < K; k0 += 32) {
    *(ushort8*)&Al[am * 40 + ak] = av0;
    *(ushort8*)&Al[am * 40 + ak + 8] = av1;
    *(ushort8*)&Bl[bn * 40 + bk] = bv0;
    *(ushort8*)&Bl[bn * 40 + bk + 8] = bv1;
    __syncthreads();

    const int kn = k0 + 32;
    if (kn < K) {
      load_a(kn, av0, av1);
      bv0 = *(const ushort8*)(Bt + (size_t)bn * K + kn + bk);
      bv1 = *(const ushort8*)(Bt + (size_t)bn * K + kn + bk + 8);
    }

    short8 af[4];
#pragma unroll
    for (int mt = 0; mt < 4; ++mt)
      af[mt] = *(const short8*)&Al[(wm + mt * 16 + l15) * 40 + l4 * 8];
#pragma unroll
    for (int nt = 0; nt < 4; ++nt) {
      short8 bfr = *(const short8*)&Bl[(wn + nt * 16 + l15) * 40 + l4 * 8];
#pragma unroll
      for (int mt = 0; mt < 4; ++mt)
        acc[mt][nt] = __builtin_amdgcn_mfma_f32_16x16x32_bf16(af[mt], bfr, acc[mt][nt], 0, 0, 0);
    }
    __syncthreads();
  }

  // C/D layout (verified m89/m91): col = lane&15, row = (lane>>4)*4 + reg
#pragma unroll
  for (int mt = 0; mt < 4; ++mt) {
    int rbase = bm + wm + mt * 16 + l4 * 4;
#pragma unroll
    for (int r = 0; r < 4; ++r) {
      int row = rbase + r;
      if (row < M) {
        float dr = dis[row];
#pragma unroll
        for (int nt = 0; nt < 4; ++nt) {
          int col = wn + nt * 16 + l15;
          C[(size_t)row * 128 + col] = f32_to_bf16(acc[mt][nt][r] * dr);
        }
      }
    }
  }
}

// ---------- pull aggregation on pre-scaled hs = dis*h ----------
// quarter-wave (16 lanes) per dest row; rows assigned via degree-sorted perm.
// Main loop 8 edges deep (8x16B gathers in flight per lane) to probe the
// latency-vs-BW question on the L2-miss path.
__global__ __launch_bounds__(256) void agg_k(const unsigned short* __restrict__ hs,
                                             const int2v* __restrict__ rowse,
                                             const int* __restrict__ cols,
                                             const float* __restrict__ dis,
                                             const int* __restrict__ perm,
                                             unsigned short* __restrict__ out_bf,
                                             const unsigned short* __restrict__ W3b,
                                             const float* __restrict__ b3,
                                             float* __restrict__ fcout,
                                             int N, float fill, int mode) {
  const int q = blockIdx.x * 16 + (threadIdx.x >> 4);   // global quarter id
  const unsigned int fl = threadIdx.x & 15;
  const int rid = perm[q];
  if (rid >= N) return;
  const char* __restrict__ hsc = (const char*)hs;
  const unsigned int flo = fl << 4;

  int2v se = rowse[rid];
  int e = se.x;
  const int end = se.y;

  f32x2 a0 = {0.f, 0.f}, a1 = {0.f, 0.f}, a2 = {0.f, 0.f}, a3 = {0.f, 0.f};

  // main loop: 8 edges/quarter in flight (32 gathers per wave iteration)
  for (; e + 8 <= end; e += 8) {
    unsigned int c0 = (unsigned int)cols[e];
    unsigned int c1 = (unsigned int)cols[e + 1];
    unsigned int c2 = (unsigned int)cols[e + 2];
    unsigned int c3 = (unsigned int)cols[e + 3];
    unsigned int c4 = (unsigned int)cols[e + 4];
    unsigned int c5 = (unsigned int)cols[e + 5];
    unsigned int c6 = (unsigned int)cols[e + 6];
    unsigned int c7 = (unsigned int)cols[e + 7];
    uint4v p0 = *(const uint4v*)(hsc + ((c0 << 8) | flo));
    uint4v p1 = *(const uint4v*)(hsc + ((c1 << 8) | flo));
    uint4v p2 = *(const uint4v*)(hsc + ((c2 << 8) | flo));
    uint4v p3 = *(const uint4v*)(hsc + ((c3 << 8) | flo));
    uint4v p4 = *(const uint4v*)(hsc + ((c4 << 8) | flo));
    uint4v p5 = *(const uint4v*)(hsc + ((c5 << 8) | flo));
    uint4v p6 = *(const uint4v*)(hsc + ((c6 << 8) | flo));
    uint4v p7 = *(const uint4v*)(hsc + ((c7 << 8) | flo));
    a0 = pk_add(a0, bf2(p0[0])); a1 = pk_add(a1, bf2(p0[1]));
    a2 = pk_add(a2, bf2(p0[2])); a3 = pk_add(a3, bf2(p0[3]));
    a0 = pk_add(a0, bf2(p1[0])); a1 = pk_add(a1, bf2(p1[1]));
    a2 = pk_add(a2, bf2(p1[2])); a3 = pk_add(a3, bf2(p1[3]));
    a0 = pk_add(a0, bf2(p2[0])); a1 = pk_add(a1, bf2(p2[1]));
    a2 = pk_add(a2, bf2(p2[2])); a3 = pk_add(a3, bf2(p2[3]));
    a0 = pk_add(a0, bf2(p3[0])); a1 = pk_add(a1, bf2(p3[1]));
    a2 = pk_add(a2, bf2(p3[2])); a3 = pk_add(a3, bf2(p3[3]));
    a0 = pk_add(a0, bf2(p4[0])); a1 = pk_add(a1, bf2(p4[1]));
    a2 = pk_add(a2, bf2(p4[2])); a3 = pk_add(a3, bf2(p4[3]));
    a0 = pk_add(a0, bf2(p5[0])); a1 = pk_add(a1, bf2(p5[1]));
    a2 = pk_add(a2, bf2(p5[2])); a3 = pk_add(a3, bf2(p5[3]));
    a0 = pk_add(a0, bf2(p6[0])); a1 = pk_add(a1, bf2(p6[1]));
    a2 = pk_add(a2, bf2(p6[2])); a3 = pk_add(a3, bf2(p6[3]));
    a0 = pk_add(a0, bf2(p7[0])); a1 = pk_add(a1, bf2(p7[1]));
    a2 = pk_add(a2, bf2(p7[2])); a3 = pk_add(a3, bf2(p7[3]));
  }
  // 4-step
  for (; e + 4 <= end; e += 4) {
    unsigned int c0 = (unsigned int)cols[e];
    unsigned int c1 = (unsigned int)cols[e + 1];
    unsigned int c2 = (unsigned int)cols[e + 2];
    unsigned int c3 = (unsigned int)cols[e + 3];
    uint4v p0 = *(const uint4v*)(hsc + ((c0 << 8) | flo));
    uint4v p1 = *(const uint4v*)(hsc + ((c1 << 8) | flo));
    uint4v p2 = *(const uint4v*)(hsc + ((c2 << 8) | flo));
    uint4v p3 = *(const uint4v*)(hsc + ((c3 << 8) | flo));
    a0 = pk_add(a0, bf2(p0[0])); a1 = pk_add(a1, bf2(p0[1]));
    a2 = pk_add(a2, bf2(p0[2])); a3 = pk_add(a3, bf2(p0[3]));
    a0 = pk_add(a0, bf2(p1[0])); a1 = pk_add(a1, bf2(p1[1]));
    a2 = pk_add(a2, bf2(p1[2])); a3 = pk_add(a3, bf2(p1[3]));
    a0 = pk_add(a0, bf2(p2[0])); a1 = pk_add(a1, bf2(p2[1]));
    a2 = pk_add(a2, bf2(p2[2])); a3 = pk_add(a3, bf2(p2[3]));
    a0 = pk_add(a0, bf2(p3[0])); a1 = pk_add(a1, bf2(p3[1]));
    a2 = pk_add(a2, bf2(p3[2])); a3 = pk_add(a3, bf2(p3[3]));
  }
  // tail: <=3 single edges
  for (; e < end; ++e) {
    unsigned int c = (unsigned int)cols[e];
    uint4v p = *(const uint4v*)(hsc + ((c << 8) | flo));
    a0 = pk_add(a0, bf2(p[0])); a1 = pk_add(a1, bf2(p[1]));
    a2 = pk_add(a2, bf2(p[2])); a3 = pk_add(a3, bf2(p[3]));
  }

  uint4v ps = *(const uint4v*)(hsc + (((unsigned int)rid << 8) | flo));
  float dr = dis[rid];
  float v[8];
  v[0] = dr * (a0.x + fill * bf16_lo(ps[0]));
  v[1] = dr * (a0.y + fill * bf16_hi(ps[0]));
  v[2] = dr * (a1.x + fill * bf16_lo(ps[1]));
  v[3] = dr * (a1.y + fill * bf16_hi(ps[1]));
  v[4] = dr * (a2.x + fill * bf16_lo(ps[2]));
  v[5] = dr * (a2.y + fill * bf16_hi(ps[2]));
  v[6] = dr * (a3.x + fill * bf16_lo(ps[3]));
  v[7] = dr * (a3.y + fill * bf16_hi(ps[3]));

  if (mode == 0) {
    uint4v o;
#pragma unroll
    for (int k = 0; k < 4; ++k) {
      float f0 = fmaxf(v[2 * k], 0.f);
      float f1 = fmaxf(v[2 * k + 1], 0.f);
      o[k] = ((unsigned int)f32_to_bf16(f1) << 16) | (unsigned int)f32_to_bf16(f0);
    }
    *(uint4v*)((char*)out_bf + (((unsigned int)rid << 8) | flo)) = o;
  } else {
    // fused classifier within the quarter
    float p[16];
#pragma unroll
    for (int c = 0; c < 16; ++c) {
      ushort8 wr = *(const ushort8*)(W3b + c * 128 + fl * 8);
      float s = v[0] * bf16u(wr[0]);
      s = fmaf(v[1], bf16u(wr[1]), s);
      s = fmaf(v[2], bf16u(wr[2]), s);
      s = fmaf(v[3], bf16u(wr[3]), s);
      s = fmaf(v[4], bf16u(wr[4]), s);
      s = fmaf(v[5], bf16u(wr[5]), s);
      s = fmaf(v[6], bf16u(wr[6]), s);
      s = fmaf(v[7], bf16u(wr[7]), s);
      p[c] = s;
    }
#pragma unroll
    for (int m = 1; m <= 8; m <<= 1)
#pragma unroll
      for (int c = 0; c < 16; ++c) p[c] += __shfl_xor(p[c], m);
    fcout[(size_t)rid * 16 + fl] = p[fl] + b3[fl];
  }
}

extern "C" void kernel_launch(void* const* d_in, const int* in_sizes, int n_in,
                              void* d_out, int out_size, void* d_ws, size_t ws_size,
                              hipStream_t stream) {
  const float* x  = (const float*)d_in[0];
  const int* edge = (const int*)d_in[1];
  const float* W1 = (const float*)d_in[2];
  const float* W2 = (const float*)d_in[3];
  const float* W3 = (const float*)d_in[4];
  const float* b3 = (const float*)d_in[5];
  float* out = (float*)d_out;

  const int HID = 128;
  const int FIN = in_sizes[2] / HID;        // 512
  const int N   = in_sizes[0] / FIN;        // 100000
  const int E   = in_sizes[1] / 2;          // 3200000
  const float fill = truncf(log2f((float)E / (float)N));  // 5.0

  char* w = (char*)d_ws;
  size_t off = 0;
  auto alloc = [&](size_t bytes) -> void* {
    void* p = w + off;
    off += (bytes + 255) & ~(size_t)255;
    return p;
  };
  const int NB = (N + 511) >> 9;            // buckets of 512 rows (196)
  float* dis      = (float*)alloc((size_t)N * 4);
  int2v* rowse    = (int2v*)alloc((size_t)N * 8);
  int* perm       = (int*)alloc((size_t)NB * 512 * 4);
  int* col_sorted = (int*)alloc((size_t)NB * BCAP * 4);
  int* bucket_cursor = (int*)alloc(256 * 4);
  unsigned int* binned = (unsigned int*)alloc((size_t)NB * BCAP * 4);
  unsigned short* W1t  = (unsigned short*)alloc((size_t)FIN * 128 * 2);
  unsigned short* W2t  = (unsigned short*)alloc(128 * 128 * 2);
  unsigned short* W3b  = (unsigned short*)alloc(16 * 128 * 2);
  unsigned short* bufA = (unsigned short*)alloc((size_t)N * 128 * 2);  // hs = dis*h
  unsigned short* bufB = (unsigned short*)alloc((size_t)N * 128 * 2);  // relu(agg1)

  const int* rows  = edge;
  const int* colsp = edge + E;

  hipMemsetAsync(bucket_cursor, 0, 256 * 4, stream);
  bin_k<<<(E + EPB - 1) / EPB, 256, 0, stream>>>(rows, colsp, bucket_cursor, binned, E);
  bucket_csr_k<<<NB, 1024, 0, stream>>>(binned, bucket_cursor, rowse, dis,
                                        col_sorted, perm, N, fill);
  const int castN = FIN * 128 + 128 * 128 + 16 * 128;
  cast_w_k<<<(castN + 255) / 256, 256, 0, stream>>>(W1, W2, W3, W1t, W2t, W3b, FIN);

  const int gm = (N + 127) / 128;
  gemm_k<<<gm, 256, 0, stream>>>(x, 1, N, FIN, W1t, dis, bufA);
  agg_k<<<NB * 32, 256, 0, stream>>>(bufA, rowse, col_sorted, dis, perm, bufB,
                                     W3b, b3, out, N, fill, 0);
  gemm_k<<<gm, 256, 0, stream>>>(bufB, 0, N, HID, W2t, dis, bufA);
  agg_k<<<NB * 32, 256, 0, stream>>>(bufA, rowse, col_sorted, dis, perm, bufB,
                                     W3b, b3, out, N, fill, 1);
}